// Round 12
// baseline (238.270 us; speedup 1.0000x reference)
//
#include <hip/hip_runtime.h>
#include <math.h>

#define S_LEN 2048
#define EMB   1024
#define NHEAD 8
#define DH    128
#define E3    3072
#define BM    64      // Q rows per workgroup (16 per wave)
#define BN    32      // K tile
#define NSPLIT 4
#define KSTRIDE  136   // K LDS row stride (elems): 272B rows, b128-aligned
#define VTSTRIDE 40    // V^T LDS row stride: 80B rows, b128-aligned
#define PTSTRIDE 40    // P LDS row stride: 80B rows, b128-aligned

typedef __bf16 bf16x8 __attribute__((ext_vector_type(8)));
typedef __bf16 bf16x4 __attribute__((ext_vector_type(4)));
typedef float  f32x4  __attribute__((ext_vector_type(4)));

// ---------------------------------------------------------------------------
// Kernel 1 (fused): blocks [0,2048) = gates + q/k hi-lo cvt;
// blocks [2048,4096) = V transpose tiles. (R8/R10-proven)
// ---------------------------------------------------------------------------
__global__ __launch_bounds__(256) void gates_cvt_transpose_kernel(
    const float* __restrict__ q, const float* __restrict__ k,
    const float* __restrict__ v,
    const float* __restrict__ Wi, const float* __restrict__ bi,
    const float* __restrict__ Wf, const float* __restrict__ bf,
    __bf16* __restrict__ Qh, __bf16* __restrict__ Ql,
    __bf16* __restrict__ Kh, __bf16* __restrict__ Kl,
    __bf16* __restrict__ Vt,
    float* __restrict__ ig, float* __restrict__ lf)
{
    const int tid = threadIdx.x;
    __shared__ union {
        float red[16][4];
        __bf16 tile[32][33];
    } sh;

    if (blockIdx.x < S_LEN) {
        const int t = blockIdx.x;
        const float4 qv = ((const float4*)q)[(size_t)t * 256 + tid];
        const float4 kv = ((const float4*)k)[(size_t)t * 256 + tid];
        const float4 vv = ((const float4*)v)[(size_t)t * 256 + tid];
        {
            size_t idx = (size_t)t * 256 + tid;
            bf16x4 hi, lo;
            hi[0]=(__bf16)qv.x; hi[1]=(__bf16)qv.y; hi[2]=(__bf16)qv.z; hi[3]=(__bf16)qv.w;
            lo[0]=(__bf16)(qv.x-(float)hi[0]); lo[1]=(__bf16)(qv.y-(float)hi[1]);
            lo[2]=(__bf16)(qv.z-(float)hi[2]); lo[3]=(__bf16)(qv.w-(float)hi[3]);
            ((bf16x4*)Qh)[idx] = hi; ((bf16x4*)Ql)[idx] = lo;
            hi[0]=(__bf16)kv.x; hi[1]=(__bf16)kv.y; hi[2]=(__bf16)kv.z; hi[3]=(__bf16)kv.w;
            lo[0]=(__bf16)(kv.x-(float)hi[0]); lo[1]=(__bf16)(kv.y-(float)hi[1]);
            lo[2]=(__bf16)(kv.z-(float)hi[2]); lo[3]=(__bf16)(kv.w-(float)hi[3]);
            ((bf16x4*)Kh)[idx] = hi; ((bf16x4*)Kl)[idx] = lo;
        }
        float acc[16];
        #pragma unroll
        for (int g = 0; g < 16; ++g) {
            const float4* w4 = (const float4*)((g < 8) ? (Wi + g * E3) : (Wf + (g - 8) * E3));
            float4 a = w4[tid], b = w4[256 + tid], c = w4[512 + tid];
            acc[g] = a.x*qv.x + a.y*qv.y + a.z*qv.z + a.w*qv.w
                   + b.x*kv.x + b.y*kv.y + b.z*kv.z + b.w*kv.w
                   + c.x*vv.x + c.y*vv.y + c.z*vv.z + c.w*vv.w;
        }
        const int w = tid >> 6, lane = tid & 63;
        #pragma unroll
        for (int g = 0; g < 16; ++g) {
            float x = acc[g];
            for (int o = 32; o > 0; o >>= 1) x += __shfl_down(x, o, 64);
            if (lane == 0) sh.red[g][w] = x;
        }
        __syncthreads();
        if (tid < 16) {
            float s = sh.red[tid][0] + sh.red[tid][1] + sh.red[tid][2] + sh.red[tid][3];
            if (tid < 8) {
                ig[tid * S_LEN + t] = s + bi[tid];
            } else {
                int h = tid - 8;
                float x = s + bf[h];
                lf[h * S_LEN + t] = fminf(x, 0.f) - log1pf(expf(-fabsf(x)));
            }
        }
    } else {
        const int tb = blockIdx.x - S_LEN;
        const int sb = (tb & 63) * 32, eb = (tb >> 6) * 32;
        #pragma unroll
        for (int i = 0; i < 4; ++i) {
            int lin = tid + i * 256;
            int sr = lin >> 5, ec = lin & 31;
            sh.tile[ec][sr] = (__bf16)v[(size_t)(sb + sr) * EMB + eb + ec];
        }
        __syncthreads();
        #pragma unroll
        for (int i = 0; i < 4; ++i) {
            int lin = tid + i * 256;
            int er = lin >> 5, sc = lin & 31;
            Vt[(size_t)(eb + er) * S_LEN + sb + sc] = sh.tile[er][sc];
        }
    }
}

// ---------------------------------------------------------------------------
// Kernel 2: cumsum of lf -> F + gate-max precompute (R8/R10-proven).
// ---------------------------------------------------------------------------
__global__ __launch_bounds__(256) void cumsum_aux_kernel(
    const float* __restrict__ lf, const float* __restrict__ ig,
    float* __restrict__ F, float* __restrict__ ug,
    float* __restrict__ umax, float* __restrict__ upmax)
{
    const int h = blockIdx.x, tid = threadIdx.x;
    __shared__ float ssum[256];
    __shared__ float morig[256];
    float loc[8];
    const int base = tid * 8;
    float s = 0.f;
    for (int i = 0; i < 8; i++) { s += lf[h * S_LEN + base + i]; loc[i] = s; }
    ssum[tid] = s;
    __syncthreads();
    for (int o = 1; o < 256; o <<= 1) {
        float add = (tid >= o) ? ssum[tid - o] : 0.f;
        __syncthreads();
        ssum[tid] += add;
        __syncthreads();
    }
    float prev = (tid > 0) ? ssum[tid - 1] : 0.f;
    float* Fh = F + h * (S_LEN + 1);
    if (tid == 0) Fh[0] = 0.f;
    float Fv[8];
    for (int i = 0; i < 8; i++) { Fv[i] = prev + loc[i]; Fh[base + i + 1] = Fv[i]; }

    const float* igh = ig + h * S_LEN;
    float pm[8];
    float runm = -1e30f;
    #pragma unroll
    for (int i = 0; i < 8; i++) {
        float u = igh[base + i] - Fv[i];
        ug[h * S_LEN + base + i] = u;
        runm = fmaxf(runm, u);
        pm[i] = runm;
    }
    morig[tid] = runm;
    __syncthreads();
    const int g0 = tid & ~3;
    float pfx = -1e30f;
    for (int j = g0; j < tid; ++j) pfx = fmaxf(pfx, morig[j]);
    #pragma unroll
    for (int i = 0; i < 8; i++)
        upmax[h * S_LEN + base + i] = fmaxf(pfx, pm[i]);
    if ((tid & 3) == 0) {
        float mm = fmaxf(fmaxf(morig[tid], morig[tid + 1]),
                         fmaxf(morig[tid + 2], morig[tid + 3]));
        umax[h * 64 + (tid >> 2)] = mm;
    }
}

// ---------------------------------------------------------------------------
// Kernel 3: flash mLSTM, BM=64 wave-private (R10 body). UNPAIRED grid:
// one wg per (qt, h, z) -> 32*8*4 = 1024 wgs = 4 wg/CU (R10 was 2/CU,
// Occupancy 16% -> latency-bound). LDS 32KB*4 = 128KB/CU fits.
// ---------------------------------------------------------------------------
__global__ __launch_bounds__(256, 4) void mlstm_mfma(
    const __bf16* __restrict__ Qhg, const __bf16* __restrict__ Qlg,
    const __bf16* __restrict__ Khg, const __bf16* __restrict__ Klg,
    const __bf16* __restrict__ Vtg,
    const float* __restrict__ ug, const float* __restrict__ umaxg,
    const float* __restrict__ upmaxg, const float* __restrict__ F,
    __bf16* __restrict__ Opart, float* __restrict__ msplit,
    float* __restrict__ lsplit)
{
    const int flat = blockIdx.x;
    const int h  = flat & 7;
    const int qt = (flat >> 3) & 31;
    const int z  = flat >> 8;
    const int tid  = threadIdx.x;
    const int lane = tid & 63, w = tid >> 6;
    const int quad = lane >> 4, l15 = lane & 15;

    __shared__ __bf16 Kh[BN * KSTRIDE], Kl[BN * KSTRIDE];
    __shared__ __bf16 Vt[DH * VTSTRIDE];
    __shared__ __bf16 Pt[4][16 * PTSTRIDE];

    const float* Fh  = F  + h * (S_LEN + 1);
    const float* ugh = ug + h * S_LEN;
    const float scale = 0.088388347648318447f; // 1/sqrt(128)
    const int kr  = tid >> 4, kc8 = tid & 15;  // K staging (b128)
    const int vr0 = tid >> 2, vc0 = tid & 3;   // Vt staging (b128)

    const int qb = qt * BM;
    const int nj = 2 * qt + 2;
    const int j0 = (z * nj) / NSPLIT, j1 = ((z + 1) * nj) / NSPLIT;

    float fq[4], upm[4];
    int sglob[4], sblk[4];
    #pragma unroll
    for (int r = 0; r < 4; ++r) {
        int s = qb + w * 16 + quad * 4 + r;
        sglob[r] = s; sblk[r] = s >> 5;
        fq[r]  = Fh[s + 1];
        upm[r] = upmaxg[h * S_LEN + s];
    }
    float m_r[4] = {-1e30f, -1e30f, -1e30f, -1e30f};
    float l_r[4] = {0.f, 0.f, 0.f, 0.f};
    f32x4 Oacc[8] = {{0,0,0,0},{0,0,0,0},{0,0,0,0},{0,0,0,0},
                     {0,0,0,0},{0,0,0,0},{0,0,0,0},{0,0,0,0}};

    bf16x8 pk[2], pl[2], pv[2];
    if (j0 < j1) {
        const int tb = j0 * BN;
        #pragma unroll
        for (int i = 0; i < 2; ++i) {
            int row = kr + 16 * i;
            size_t g = (size_t)(tb + row) * EMB + h * DH + kc8 * 8;
            pk[i] = *(const bf16x8*)(Khg + g);
            pl[i] = *(const bf16x8*)(Klg + g);
            pv[i] = *(const bf16x8*)(Vtg + (size_t)(h * DH + vr0 + 64 * i) * S_LEN + tb + vc0 * 8);
        }
    }

    for (int j = j0; j < j1; ++j) {
        const int tb = j * BN;
        __syncthreads(); // A: prev-iter LDS consumers done
        #pragma unroll
        for (int i = 0; i < 2; ++i) {
            int row = kr + 16 * i;
            *(bf16x8*)&Kh[row * KSTRIDE + kc8 * 8] = pk[i];
            *(bf16x8*)&Kl[row * KSTRIDE + kc8 * 8] = pl[i];
            *(bf16x8*)&Vt[(vr0 + 64 * i) * VTSTRIDE + vc0 * 8] = pv[i];
        }
        __syncthreads(); // B: tiles staged
        if (j + 1 < j1) {  // prefetch next tile
            const int tb2 = tb + BN;
            #pragma unroll
            for (int i = 0; i < 2; ++i) {
                int row = kr + 16 * i;
                size_t g = (size_t)(tb2 + row) * EMB + h * DH + kc8 * 8;
                pk[i] = *(const bf16x8*)(Khg + g);
                pl[i] = *(const bf16x8*)(Klg + g);
                pv[i] = *(const bf16x8*)(Vtg + (size_t)(h * DH + vr0 + 64 * i) * S_LEN + tb2 + vc0 * 8);
            }
        }
        // ---- Q hi/lo A-frags direct from global (wave-private rows) ----
        bf16x8 qh[4], ql[4];
        {
            const size_t qrow = (size_t)(qb + w * 16 + l15) * EMB + h * DH + quad * 8;
            #pragma unroll
            for (int kk = 0; kk < 4; ++kk) {
                qh[kk] = *(const bf16x8*)(Qhg + qrow + kk * 32);
                ql[kk] = *(const bf16x8*)(Qlg + qrow + kk * 32);
            }
        }
        // ---- S = Q K^T (split-bf16), both t-halves per wave ----
        f32x4 S0 = {0,0,0,0}, S1 = {0,0,0,0};
        #pragma unroll
        for (int kk = 0; kk < 4; ++kk) {
            const int co = kk * 32 + quad * 8;
            bf16x8 bh0 = *(const bf16x8*)&Kh[l15 * KSTRIDE + co];
            bf16x8 bl0 = *(const bf16x8*)&Kl[l15 * KSTRIDE + co];
            S0 = __builtin_amdgcn_mfma_f32_16x16x32_bf16(qh[kk], bh0, S0, 0, 0, 0);
            S0 = __builtin_amdgcn_mfma_f32_16x16x32_bf16(qh[kk], bl0, S0, 0, 0, 0);
            S0 = __builtin_amdgcn_mfma_f32_16x16x32_bf16(ql[kk], bh0, S0, 0, 0, 0);
            bf16x8 bh1 = *(const bf16x8*)&Kh[(16 + l15) * KSTRIDE + co];
            bf16x8 bl1 = *(const bf16x8*)&Kl[(16 + l15) * KSTRIDE + co];
            S1 = __builtin_amdgcn_mfma_f32_16x16x32_bf16(qh[kk], bh1, S1, 0, 0, 0);
            S1 = __builtin_amdgcn_mfma_f32_16x16x32_bf16(qh[kk], bl1, S1, 0, 0, 0);
            S1 = __builtin_amdgcn_mfma_f32_16x16x32_bf16(ql[kk], bh1, S1, 0, 0, 0);
        }
        // ---- gates + online softmax, fully wave-private ----
        const int t0 = tb + l15, t1 = tb + 16 + l15;
        const float ut0 = ugh[t0], ut1 = ugh[t1];
        const float umj = umaxg[h * 64 + j];
        #pragma unroll
        for (int r = 0; r < 4; ++r) {
            float mt = (j < sblk[r]) ? (fq[r] + umj)
                     : (j == sblk[r]) ? (fq[r] + upm[r]) : -1e30f;
            float mn = fmaxf(m_r[r], mt);
            float alpha = __expf(m_r[r] - mn);
            m_r[r] = mn;
            l_r[r] *= alpha;
            #pragma unroll
            for (int nt = 0; nt < 8; ++nt) Oacc[nt][r] *= alpha;
            float p0 = __expf(fq[r] + ut0 - mn) * S0[r] * scale;
            float p1 = __expf(fq[r] + ut1 - mn) * S1[r] * scale;
            if (j >= sblk[r]) {
                if (t0 > sglob[r]) p0 = 0.f;
                if (t1 > sglob[r]) p1 = 0.f;
            }
            float x = p0 + p1;
            #pragma unroll
            for (int o = 1; o < 16; o <<= 1) x += __shfl_xor(x, o);
            l_r[r] += x;
            const int prow = (quad * 4 + r) * PTSTRIDE;
            Pt[w][prow + l15]      = (__bf16)p0;
            Pt[w][prow + 16 + l15] = (__bf16)p1;
        }
        // ---- O += P V (P from own wave's LDS scratch, no barrier) ----
        bf16x8 pa = *(const bf16x8*)&Pt[w][l15 * PTSTRIDE + quad * 8];
        #pragma unroll
        for (int nt = 0; nt < 8; ++nt) {
            bf16x8 vb = *(const bf16x8*)&Vt[(nt * 16 + l15) * VTSTRIDE + quad * 8];
            Oacc[nt] = __builtin_amdgcn_mfma_f32_16x16x32_bf16(pa, vb, Oacc[nt], 0, 0, 0);
        }
    }
    // ---- epilogue: unnormalized bf16 partials ----
    __bf16* Oz = Opart + (size_t)z * S_LEN * EMB;
    #pragma unroll
    for (int nt = 0; nt < 8; ++nt) {
        #pragma unroll
        for (int r = 0; r < 4; ++r) {
            Oz[(size_t)sglob[r] * EMB + h * DH + nt * 16 + l15] = (__bf16)Oacc[nt][r];
        }
    }
    if (l15 == 0) {
        #pragma unroll
        for (int r = 0; r < 4; ++r) {
            msplit[(z * NHEAD + h) * S_LEN + sglob[r]] = m_r[r];
            lsplit[(z * NHEAD + h) * S_LEN + sglob[r]] = l_r[r];
        }
    }
}

// ---------------------------------------------------------------------------
// Kernel 4: combine split-K partials + normalize + LN. Vectorized:
// 2 rows/block, 128 thr/row, bf16x8 Opart loads, float4 stores.
// ---------------------------------------------------------------------------
__global__ __launch_bounds__(256) void combine_ln_kernel(
    const __bf16* __restrict__ Opart, const float* __restrict__ msplit,
    const float* __restrict__ lsplit, const float* __restrict__ lnw,
    float* __restrict__ out)
{
    const int tid = threadIdx.x;
    const int r  = tid >> 7;          // row within block (0/1)
    const int wr = (tid >> 6) & 1;    // wave within row
    const int c0 = (tid & 127) * 8;   // 8 contiguous cols per thread
    const int hh = c0 >> 7;
    const int s  = blockIdx.x * 2 + r;
    __shared__ float redsum[2][2], redvar[2][2];

    // per-(row,head) normalizer (redundant across the head's 16 threads; L1-hot)
    float m = -1e30f, es[NSPLIT], l = 0.f;
    #pragma unroll
    for (int zz = 0; zz < NSPLIT; ++zz)
        m = fmaxf(m, msplit[(zz * NHEAD + hh) * S_LEN + s]);
    #pragma unroll
    for (int zz = 0; zz < NSPLIT; ++zz) {
        es[zz] = __expf(msplit[(zz * NHEAD + hh) * S_LEN + s] - m);
        l += es[zz] * lsplit[(zz * NHEAD + hh) * S_LEN + s];
    }
    const float rn = 1.f / (fmaxf(fabsf(l), __expf(-m)) + 1e-6f);

    const size_t SE = (size_t)S_LEN * EMB;
    float x[8] = {0,0,0,0,0,0,0,0};
    #pragma unroll
    for (int zz = 0; zz < NSPLIT; ++zz) {
        bf16x8 o = *(const bf16x8*)(Opart + zz * SE + (size_t)s * EMB + c0);
        #pragma unroll
        for (int e = 0; e < 8; ++e) x[e] += es[zz] * (float)o[e];
    }
    float sum = 0.f;
    #pragma unroll
    for (int e = 0; e < 8; ++e) { x[e] *= rn; sum += x[e]; }
    for (int o = 32; o > 0; o >>= 1) sum += __shfl_down(sum, o, 64);
    if ((tid & 63) == 0) redsum[r][wr] = sum;
    __syncthreads();
    sum = redsum[r][0] + redsum[r][1];
    const float mu = sum * (1.f / EMB);
    float vs = 0.f;
    #pragma unroll
    for (int e = 0; e < 8; ++e) { float d = x[e] - mu; vs += d * d; }
    for (int o = 32; o > 0; o >>= 1) vs += __shfl_down(vs, o, 64);
    if ((tid & 63) == 0) redvar[r][wr] = vs;
    __syncthreads();
    vs = redvar[r][0] + redvar[r][1];
    const float rstd = rsqrtf(vs * (1.f / EMB) + 1e-5f);
    const float4 w0 = *(const float4*)(lnw + c0);
    const float4 w1 = *(const float4*)(lnw + c0 + 4);
    float4 o0, o1;
    o0.x = (x[0]-mu)*rstd*(1.f+w0.x); o0.y = (x[1]-mu)*rstd*(1.f+w0.y);
    o0.z = (x[2]-mu)*rstd*(1.f+w0.z); o0.w = (x[3]-mu)*rstd*(1.f+w0.w);
    o1.x = (x[4]-mu)*rstd*(1.f+w1.x); o1.y = (x[5]-mu)*rstd*(1.f+w1.y);
    o1.z = (x[6]-mu)*rstd*(1.f+w1.z); o1.w = (x[7]-mu)*rstd*(1.f+w1.w);
    *(float4*)(out + (size_t)s * EMB + c0)     = o0;
    *(float4*)(out + (size_t)s * EMB + c0 + 4) = o1;
}

// ---------------------------------------------------------------------------
extern "C" void kernel_launch(void* const* d_in, const int* in_sizes, int n_in,
                              void* d_out, int out_size, void* d_ws, size_t ws_size,
                              hipStream_t stream)
{
    const float* q   = (const float*)d_in[0];
    const float* k   = (const float*)d_in[1];
    const float* v   = (const float*)d_in[2];
    const float* Wi  = (const float*)d_in[3];
    const float* bi  = (const float*)d_in[4];
    const float* Wf  = (const float*)d_in[5];
    const float* bf  = (const float*)d_in[6];
    const float* lnw = (const float*)d_in[7];
    float* out = (float*)d_out;

    // workspace layout (38.6 MB, proven safe; 47.3 MB overflowed in R9):
    float* ws = (float*)d_ws;
    float* ig    = ws;                          // NH*S
    float* lf    = ig + NHEAD * S_LEN;          // NH*S
    float* F     = lf + NHEAD * S_LEN;          // NH*(S+1)
    float* ugw   = F + NHEAD * (S_LEN + 1);     // NH*S
    float* umaxw = ugw + NHEAD * S_LEN;         // NH*64
    float* upmaxw= umaxw + NHEAD * 64;          // NH*S
    __bf16* Qh = (__bf16*)(upmaxw + NHEAD * S_LEN);
    const size_t SEb = (size_t)S_LEN * EMB;
    __bf16* Ql  = Qh + SEb;
    __bf16* Kh  = Ql + SEb;
    __bf16* Kl  = Kh + SEb;
    __bf16* Vtg = Kl + SEb;
    __bf16* Opart = Vtg + SEb;                  // NSPLIT*S*EMB bf16 (16 MB)
    float* msplit = (float*)(Opart + (size_t)NSPLIT * SEb);
    float* lsplit = msplit + NSPLIT * NHEAD * S_LEN;

    gates_cvt_transpose_kernel<<<2 * S_LEN, 256, 0, stream>>>(
        q, k, v, Wi, bi, Wf, bf, Qh, Ql, Kh, Kl, Vtg, ig, lf);
    cumsum_aux_kernel<<<NHEAD, 256, 0, stream>>>(lf, ig, F, ugw, umaxw, upmaxw);
    mlstm_mfma<<<32 * NHEAD * NSPLIT, 256, 0, stream>>>(
        Qh, Ql, Kh, Kl, Vtg, ugw, umaxw, upmaxw, F, Opart, msplit, lsplit);
    combine_ln_kernel<<<S_LEN / 2, 256, 0, stream>>>(Opart, msplit, lsplit, lnw, out);
}

// Round 13
// 159.469 us; speedup vs baseline: 1.4942x; 1.4942x over previous
//
#include <hip/hip_runtime.h>
#include <math.h>

#define S_LEN 2048
#define EMB   1024
#define NHEAD 8
#define DH    128
#define E3    3072
#define BM    64      // Q rows per workgroup (16 per wave)
#define BN    32      // K tile
#define NSPLIT 4
#define KSTRIDE  136   // K LDS row stride (elems): 272B rows, b128-aligned
#define VTSTRIDE 40    // V^T LDS row stride: 80B rows, b128-aligned
#define PTSTRIDE 40    // P LDS row stride: 80B rows, b128-aligned

typedef __bf16 bf16x8 __attribute__((ext_vector_type(8)));
typedef __bf16 bf16x4 __attribute__((ext_vector_type(4)));
typedef float  f32x4  __attribute__((ext_vector_type(4)));

// ---------------------------------------------------------------------------
// Kernel 1 (fused): blocks [0,2048) = gates + q/k hi-lo cvt;
// blocks [2048,4096) = V transpose tiles. (R8/R10-proven)
// ---------------------------------------------------------------------------
__global__ __launch_bounds__(256) void gates_cvt_transpose_kernel(
    const float* __restrict__ q, const float* __restrict__ k,
    const float* __restrict__ v,
    const float* __restrict__ Wi, const float* __restrict__ bi,
    const float* __restrict__ Wf, const float* __restrict__ bf,
    __bf16* __restrict__ Qh, __bf16* __restrict__ Ql,
    __bf16* __restrict__ Kh, __bf16* __restrict__ Kl,
    __bf16* __restrict__ Vt,
    float* __restrict__ ig, float* __restrict__ lf)
{
    const int tid = threadIdx.x;
    __shared__ union {
        float red[16][4];
        __bf16 tile[32][33];
    } sh;

    if (blockIdx.x < S_LEN) {
        const int t = blockIdx.x;
        const float4 qv = ((const float4*)q)[(size_t)t * 256 + tid];
        const float4 kv = ((const float4*)k)[(size_t)t * 256 + tid];
        const float4 vv = ((const float4*)v)[(size_t)t * 256 + tid];
        {
            size_t idx = (size_t)t * 256 + tid;
            bf16x4 hi, lo;
            hi[0]=(__bf16)qv.x; hi[1]=(__bf16)qv.y; hi[2]=(__bf16)qv.z; hi[3]=(__bf16)qv.w;
            lo[0]=(__bf16)(qv.x-(float)hi[0]); lo[1]=(__bf16)(qv.y-(float)hi[1]);
            lo[2]=(__bf16)(qv.z-(float)hi[2]); lo[3]=(__bf16)(qv.w-(float)hi[3]);
            ((bf16x4*)Qh)[idx] = hi; ((bf16x4*)Ql)[idx] = lo;
            hi[0]=(__bf16)kv.x; hi[1]=(__bf16)kv.y; hi[2]=(__bf16)kv.z; hi[3]=(__bf16)kv.w;
            lo[0]=(__bf16)(kv.x-(float)hi[0]); lo[1]=(__bf16)(kv.y-(float)hi[1]);
            lo[2]=(__bf16)(kv.z-(float)hi[2]); lo[3]=(__bf16)(kv.w-(float)hi[3]);
            ((bf16x4*)Kh)[idx] = hi; ((bf16x4*)Kl)[idx] = lo;
        }
        float acc[16];
        #pragma unroll
        for (int g = 0; g < 16; ++g) {
            const float4* w4 = (const float4*)((g < 8) ? (Wi + g * E3) : (Wf + (g - 8) * E3));
            float4 a = w4[tid], b = w4[256 + tid], c = w4[512 + tid];
            acc[g] = a.x*qv.x + a.y*qv.y + a.z*qv.z + a.w*qv.w
                   + b.x*kv.x + b.y*kv.y + b.z*kv.z + b.w*kv.w
                   + c.x*vv.x + c.y*vv.y + c.z*vv.z + c.w*vv.w;
        }
        const int w = tid >> 6, lane = tid & 63;
        #pragma unroll
        for (int g = 0; g < 16; ++g) {
            float x = acc[g];
            for (int o = 32; o > 0; o >>= 1) x += __shfl_down(x, o, 64);
            if (lane == 0) sh.red[g][w] = x;
        }
        __syncthreads();
        if (tid < 16) {
            float s = sh.red[tid][0] + sh.red[tid][1] + sh.red[tid][2] + sh.red[tid][3];
            if (tid < 8) {
                ig[tid * S_LEN + t] = s + bi[tid];
            } else {
                int h = tid - 8;
                float x = s + bf[h];
                lf[h * S_LEN + t] = fminf(x, 0.f) - log1pf(expf(-fabsf(x)));
            }
        }
    } else {
        const int tb = blockIdx.x - S_LEN;
        const int sb = (tb & 63) * 32, eb = (tb >> 6) * 32;
        #pragma unroll
        for (int i = 0; i < 4; ++i) {
            int lin = tid + i * 256;
            int sr = lin >> 5, ec = lin & 31;
            sh.tile[ec][sr] = (__bf16)v[(size_t)(sb + sr) * EMB + eb + ec];
        }
        __syncthreads();
        #pragma unroll
        for (int i = 0; i < 4; ++i) {
            int lin = tid + i * 256;
            int er = lin >> 5, sc = lin & 31;
            Vt[(size_t)(eb + er) * S_LEN + sb + sc] = sh.tile[er][sc];
        }
    }
}

// ---------------------------------------------------------------------------
// Kernel 2: cumsum of lf -> F + gate-max precompute (R8/R10-proven).
// ---------------------------------------------------------------------------
__global__ __launch_bounds__(256) void cumsum_aux_kernel(
    const float* __restrict__ lf, const float* __restrict__ ig,
    float* __restrict__ F, float* __restrict__ ug,
    float* __restrict__ umax, float* __restrict__ upmax)
{
    const int h = blockIdx.x, tid = threadIdx.x;
    __shared__ float ssum[256];
    __shared__ float morig[256];
    float loc[8];
    const int base = tid * 8;
    float s = 0.f;
    for (int i = 0; i < 8; i++) { s += lf[h * S_LEN + base + i]; loc[i] = s; }
    ssum[tid] = s;
    __syncthreads();
    for (int o = 1; o < 256; o <<= 1) {
        float add = (tid >= o) ? ssum[tid - o] : 0.f;
        __syncthreads();
        ssum[tid] += add;
        __syncthreads();
    }
    float prev = (tid > 0) ? ssum[tid - 1] : 0.f;
    float* Fh = F + h * (S_LEN + 1);
    if (tid == 0) Fh[0] = 0.f;
    float Fv[8];
    for (int i = 0; i < 8; i++) { Fv[i] = prev + loc[i]; Fh[base + i + 1] = Fv[i]; }

    const float* igh = ig + h * S_LEN;
    float pm[8];
    float runm = -1e30f;
    #pragma unroll
    for (int i = 0; i < 8; i++) {
        float u = igh[base + i] - Fv[i];
        ug[h * S_LEN + base + i] = u;
        runm = fmaxf(runm, u);
        pm[i] = runm;
    }
    morig[tid] = runm;
    __syncthreads();
    const int g0 = tid & ~3;
    float pfx = -1e30f;
    for (int j = g0; j < tid; ++j) pfx = fmaxf(pfx, morig[j]);
    #pragma unroll
    for (int i = 0; i < 8; i++)
        upmax[h * S_LEN + base + i] = fmaxf(pfx, pm[i]);
    if ((tid & 3) == 0) {
        float mm = fmaxf(fmaxf(morig[tid], morig[tid + 1]),
                         fmaxf(morig[tid + 2], morig[tid + 3]));
        umax[h * 64 + (tid >> 2)] = mm;
    }
}

// ---------------------------------------------------------------------------
// Kernel 3: flash mLSTM, BM=64 wave-private — R10-proven version VERBATIM
// (paired {x,31-x} grid 512, launch_bounds(256,2) -> VGPR 96, no spill;
// R12's (256,4) cap collapsed the allocator to 64 VGPR + 120 MB scratch).
// ---------------------------------------------------------------------------
__global__ __launch_bounds__(256, 2) void mlstm_mfma(
    const __bf16* __restrict__ Qhg, const __bf16* __restrict__ Qlg,
    const __bf16* __restrict__ Khg, const __bf16* __restrict__ Klg,
    const __bf16* __restrict__ Vtg,
    const float* __restrict__ ug, const float* __restrict__ umaxg,
    const float* __restrict__ upmaxg, const float* __restrict__ F,
    __bf16* __restrict__ Opart, float* __restrict__ msplit,
    float* __restrict__ lsplit)
{
    const int flat = blockIdx.x;
    const int h = flat & 7;
    const int rest = flat >> 3;
    const int xx = rest & 15, z = rest >> 4;
    const int tid  = threadIdx.x;
    const int lane = tid & 63, w = tid >> 6;
    const int quad = lane >> 4, l15 = lane & 15;

    __shared__ __bf16 Kh[BN * KSTRIDE], Kl[BN * KSTRIDE];
    __shared__ __bf16 Vt[DH * VTSTRIDE];
    __shared__ __bf16 Pt[4][16 * PTSTRIDE];

    const float* Fh  = F  + h * (S_LEN + 1);
    const float* ugh = ug + h * S_LEN;
    const float scale = 0.088388347648318447f; // 1/sqrt(128)
    const int kr  = tid >> 4, kc8 = tid & 15;  // K staging (b128)
    const int vr0 = tid >> 2, vc0 = tid & 3;   // Vt staging (b128)

    for (int pair = 0; pair < 2; ++pair) {
        const int qt = (pair == 0) ? xx : 31 - xx;
        const int qb = qt * BM;
        const int nj = 2 * qt + 2;
        const int j0 = (z * nj) / NSPLIT, j1 = ((z + 1) * nj) / NSPLIT;

        float fq[4], upm[4];
        int sglob[4], sblk[4];
        #pragma unroll
        for (int r = 0; r < 4; ++r) {
            int s = qb + w * 16 + quad * 4 + r;
            sglob[r] = s; sblk[r] = s >> 5;
            fq[r]  = Fh[s + 1];
            upm[r] = upmaxg[h * S_LEN + s];
        }
        float m_r[4] = {-1e30f, -1e30f, -1e30f, -1e30f};
        float l_r[4] = {0.f, 0.f, 0.f, 0.f};
        f32x4 Oacc[8] = {{0,0,0,0},{0,0,0,0},{0,0,0,0},{0,0,0,0},
                         {0,0,0,0},{0,0,0,0},{0,0,0,0},{0,0,0,0}};

        bf16x8 pk[2], pl[2], pv[2];
        if (j0 < j1) {
            const int tb = j0 * BN;
            #pragma unroll
            for (int i = 0; i < 2; ++i) {
                int row = kr + 16 * i;
                size_t g = (size_t)(tb + row) * EMB + h * DH + kc8 * 8;
                pk[i] = *(const bf16x8*)(Khg + g);
                pl[i] = *(const bf16x8*)(Klg + g);
                pv[i] = *(const bf16x8*)(Vtg + (size_t)(h * DH + vr0 + 64 * i) * S_LEN + tb + vc0 * 8);
            }
        }

        for (int j = j0; j < j1; ++j) {
            const int tb = j * BN;
            __syncthreads(); // A: prev-iter LDS consumers done
            #pragma unroll
            for (int i = 0; i < 2; ++i) {
                int row = kr + 16 * i;
                *(bf16x8*)&Kh[row * KSTRIDE + kc8 * 8] = pk[i];
                *(bf16x8*)&Kl[row * KSTRIDE + kc8 * 8] = pl[i];
                *(bf16x8*)&Vt[(vr0 + 64 * i) * VTSTRIDE + vc0 * 8] = pv[i];
            }
            __syncthreads(); // B: tiles staged
            if (j + 1 < j1) {  // prefetch next tile
                const int tb2 = tb + BN;
                #pragma unroll
                for (int i = 0; i < 2; ++i) {
                    int row = kr + 16 * i;
                    size_t g = (size_t)(tb2 + row) * EMB + h * DH + kc8 * 8;
                    pk[i] = *(const bf16x8*)(Khg + g);
                    pl[i] = *(const bf16x8*)(Klg + g);
                    pv[i] = *(const bf16x8*)(Vtg + (size_t)(h * DH + vr0 + 64 * i) * S_LEN + tb2 + vc0 * 8);
                }
            }
            // ---- Q hi/lo A-frags direct from global (wave-private rows) ----
            bf16x8 qh[4], ql[4];
            {
                const size_t qrow = (size_t)(qb + w * 16 + l15) * EMB + h * DH + quad * 8;
                #pragma unroll
                for (int kk = 0; kk < 4; ++kk) {
                    qh[kk] = *(const bf16x8*)(Qhg + qrow + kk * 32);
                    ql[kk] = *(const bf16x8*)(Qlg + qrow + kk * 32);
                }
            }
            // ---- S = Q K^T (split-bf16), both t-halves per wave ----
            f32x4 S0 = {0,0,0,0}, S1 = {0,0,0,0};
            #pragma unroll
            for (int kk = 0; kk < 4; ++kk) {
                const int co = kk * 32 + quad * 8;
                bf16x8 bh0 = *(const bf16x8*)&Kh[l15 * KSTRIDE + co];
                bf16x8 bl0 = *(const bf16x8*)&Kl[l15 * KSTRIDE + co];
                S0 = __builtin_amdgcn_mfma_f32_16x16x32_bf16(qh[kk], bh0, S0, 0, 0, 0);
                S0 = __builtin_amdgcn_mfma_f32_16x16x32_bf16(qh[kk], bl0, S0, 0, 0, 0);
                S0 = __builtin_amdgcn_mfma_f32_16x16x32_bf16(ql[kk], bh0, S0, 0, 0, 0);
                bf16x8 bh1 = *(const bf16x8*)&Kh[(16 + l15) * KSTRIDE + co];
                bf16x8 bl1 = *(const bf16x8*)&Kl[(16 + l15) * KSTRIDE + co];
                S1 = __builtin_amdgcn_mfma_f32_16x16x32_bf16(qh[kk], bh1, S1, 0, 0, 0);
                S1 = __builtin_amdgcn_mfma_f32_16x16x32_bf16(qh[kk], bl1, S1, 0, 0, 0);
                S1 = __builtin_amdgcn_mfma_f32_16x16x32_bf16(ql[kk], bh1, S1, 0, 0, 0);
            }
            // ---- gates + online softmax, fully wave-private ----
            const int t0 = tb + l15, t1 = tb + 16 + l15;
            const float ut0 = ugh[t0], ut1 = ugh[t1];
            const float umj = umaxg[h * 64 + j];
            #pragma unroll
            for (int r = 0; r < 4; ++r) {
                float mt = (j < sblk[r]) ? (fq[r] + umj)
                         : (j == sblk[r]) ? (fq[r] + upm[r]) : -1e30f;
                float mn = fmaxf(m_r[r], mt);
                float alpha = __expf(m_r[r] - mn);
                m_r[r] = mn;
                l_r[r] *= alpha;
                #pragma unroll
                for (int nt = 0; nt < 8; ++nt) Oacc[nt][r] *= alpha;
                float p0 = __expf(fq[r] + ut0 - mn) * S0[r] * scale;
                float p1 = __expf(fq[r] + ut1 - mn) * S1[r] * scale;
                if (j >= sblk[r]) {
                    if (t0 > sglob[r]) p0 = 0.f;
                    if (t1 > sglob[r]) p1 = 0.f;
                }
                float x = p0 + p1;
                #pragma unroll
                for (int o = 1; o < 16; o <<= 1) x += __shfl_xor(x, o);
                l_r[r] += x;
                const int prow = (quad * 4 + r) * PTSTRIDE;
                Pt[w][prow + l15]      = (__bf16)p0;
                Pt[w][prow + 16 + l15] = (__bf16)p1;
            }
            // ---- O += P V (P from own wave's LDS scratch, no barrier) ----
            bf16x8 pa = *(const bf16x8*)&Pt[w][l15 * PTSTRIDE + quad * 8];
            #pragma unroll
            for (int nt = 0; nt < 8; ++nt) {
                bf16x8 vb = *(const bf16x8*)&Vt[(nt * 16 + l15) * VTSTRIDE + quad * 8];
                Oacc[nt] = __builtin_amdgcn_mfma_f32_16x16x32_bf16(pa, vb, Oacc[nt], 0, 0, 0);
            }
        }
        // ---- epilogue: unnormalized bf16 partials ----
        __bf16* Oz = Opart + (size_t)z * S_LEN * EMB;
        #pragma unroll
        for (int nt = 0; nt < 8; ++nt) {
            #pragma unroll
            for (int r = 0; r < 4; ++r) {
                Oz[(size_t)sglob[r] * EMB + h * DH + nt * 16 + l15] = (__bf16)Oacc[nt][r];
            }
        }
        if (l15 == 0) {
            #pragma unroll
            for (int r = 0; r < 4; ++r) {
                msplit[(z * NHEAD + h) * S_LEN + sglob[r]] = m_r[r];
                lsplit[(z * NHEAD + h) * S_LEN + sglob[r]] = l_r[r];
            }
        }
    }
}

// ---------------------------------------------------------------------------
// Kernel 4: combine split-K partials + normalize + LN. Vectorized (R12):
// 2 rows/block, 128 thr/row, bf16x8 Opart loads, float4 stores.
// ---------------------------------------------------------------------------
__global__ __launch_bounds__(256) void combine_ln_kernel(
    const __bf16* __restrict__ Opart, const float* __restrict__ msplit,
    const float* __restrict__ lsplit, const float* __restrict__ lnw,
    float* __restrict__ out)
{
    const int tid = threadIdx.x;
    const int r  = tid >> 7;          // row within block (0/1)
    const int wr = (tid >> 6) & 1;    // wave within row
    const int c0 = (tid & 127) * 8;   // 8 contiguous cols per thread
    const int hh = c0 >> 7;
    const int s  = blockIdx.x * 2 + r;
    __shared__ float redsum[2][2], redvar[2][2];

    float m = -1e30f, es[NSPLIT], l = 0.f;
    #pragma unroll
    for (int zz = 0; zz < NSPLIT; ++zz)
        m = fmaxf(m, msplit[(zz * NHEAD + hh) * S_LEN + s]);
    #pragma unroll
    for (int zz = 0; zz < NSPLIT; ++zz) {
        es[zz] = __expf(msplit[(zz * NHEAD + hh) * S_LEN + s] - m);
        l += es[zz] * lsplit[(zz * NHEAD + hh) * S_LEN + s];
    }
    const float rn = 1.f / (fmaxf(fabsf(l), __expf(-m)) + 1e-6f);

    const size_t SE = (size_t)S_LEN * EMB;
    float x[8] = {0,0,0,0,0,0,0,0};
    #pragma unroll
    for (int zz = 0; zz < NSPLIT; ++zz) {
        bf16x8 o = *(const bf16x8*)(Opart + zz * SE + (size_t)s * EMB + c0);
        #pragma unroll
        for (int e = 0; e < 8; ++e) x[e] += es[zz] * (float)o[e];
    }
    float sum = 0.f;
    #pragma unroll
    for (int e = 0; e < 8; ++e) { x[e] *= rn; sum += x[e]; }
    for (int o = 32; o > 0; o >>= 1) sum += __shfl_down(sum, o, 64);
    if ((tid & 63) == 0) redsum[r][wr] = sum;
    __syncthreads();
    sum = redsum[r][0] + redsum[r][1];
    const float mu = sum * (1.f / EMB);
    float vs = 0.f;
    #pragma unroll
    for (int e = 0; e < 8; ++e) { float d = x[e] - mu; vs += d * d; }
    for (int o = 32; o > 0; o >>= 1) vs += __shfl_down(vs, o, 64);
    if ((tid & 63) == 0) redvar[r][wr] = vs;
    __syncthreads();
    vs = redvar[r][0] + redvar[r][1];
    const float rstd = rsqrtf(vs * (1.f / EMB) + 1e-5f);
    const float4 w0 = *(const float4*)(lnw + c0);
    const float4 w1 = *(const float4*)(lnw + c0 + 4);
    float4 o0, o1;
    o0.x = (x[0]-mu)*rstd*(1.f+w0.x); o0.y = (x[1]-mu)*rstd*(1.f+w0.y);
    o0.z = (x[2]-mu)*rstd*(1.f+w0.z); o0.w = (x[3]-mu)*rstd*(1.f+w0.w);
    o1.x = (x[4]-mu)*rstd*(1.f+w1.x); o1.y = (x[5]-mu)*rstd*(1.f+w1.y);
    o1.z = (x[6]-mu)*rstd*(1.f+w1.z); o1.w = (x[7]-mu)*rstd*(1.f+w1.w);
    *(float4*)(out + (size_t)s * EMB + c0)     = o0;
    *(float4*)(out + (size_t)s * EMB + c0 + 4) = o1;
}

// ---------------------------------------------------------------------------
extern "C" void kernel_launch(void* const* d_in, const int* in_sizes, int n_in,
                              void* d_out, int out_size, void* d_ws, size_t ws_size,
                              hipStream_t stream)
{
    const float* q   = (const float*)d_in[0];
    const float* k   = (const float*)d_in[1];
    const float* v   = (const float*)d_in[2];
    const float* Wi  = (const float*)d_in[3];
    const float* bi  = (const float*)d_in[4];
    const float* Wf  = (const float*)d_in[5];
    const float* bf  = (const float*)d_in[6];
    const float* lnw = (const float*)d_in[7];
    float* out = (float*)d_out;

    // workspace layout (38.6 MB, proven safe; 47.3 MB overflowed in R9):
    float* ws = (float*)d_ws;
    float* ig    = ws;                          // NH*S
    float* lf    = ig + NHEAD * S_LEN;          // NH*S
    float* F     = lf + NHEAD * S_LEN;          // NH*(S+1)
    float* ugw   = F + NHEAD * (S_LEN + 1);     // NH*S
    float* umaxw = ugw + NHEAD * S_LEN;         // NH*64
    float* upmaxw= umaxw + NHEAD * 64;          // NH*S
    __bf16* Qh = (__bf16*)(upmaxw + NHEAD * S_LEN);
    const size_t SEb = (size_t)S_LEN * EMB;
    __bf16* Ql  = Qh + SEb;
    __bf16* Kh  = Ql + SEb;
    __bf16* Kl  = Kh + SEb;
    __bf16* Vtg = Kl + SEb;
    __bf16* Opart = Vtg + SEb;                  // NSPLIT*S*EMB bf16 (16 MB)
    float* msplit = (float*)(Opart + (size_t)NSPLIT * SEb);
    float* lsplit = msplit + NSPLIT * NHEAD * S_LEN;

    gates_cvt_transpose_kernel<<<2 * S_LEN, 256, 0, stream>>>(
        q, k, v, Wi, bi, Wf, bf, Qh, Ql, Kh, Kl, Vtg, ig, lf);
    cumsum_aux_kernel<<<NHEAD, 256, 0, stream>>>(lf, ig, F, ugw, umaxw, upmaxw);
    mlstm_mfma<<<16 * NHEAD * NSPLIT, 256, 0, stream>>>(
        Qh, Ql, Kh, Kl, Vtg, ugw, umaxw, upmaxw, F, Opart, msplit, lsplit);
    combine_ln_kernel<<<S_LEN / 2, 256, 0, stream>>>(Opart, msplit, lsplit, lnw, out);
}